// Round 2
// baseline (923.029 us; speedup 1.0000x reference)
//
#include <hip/hip_runtime.h>
#include <hip/hip_bf16.h>

// Shapes (fixed by the problem)
#define VV 50000
#define EE 128
#define HH 128
#define OO 128
#define BB 64
#define TT 512

typedef __bf16 bf16_t;
typedef __attribute__((ext_vector_type(8))) __bf16 bf16x8;
typedef __attribute__((ext_vector_type(4))) float floatx4;

__device__ __forceinline__ bf16x8 ldb8(const bf16_t* p) {
    return *reinterpret_cast<const bf16x8*>(p);
}

// load 8 consecutive fp32, round to bf16 fragment (two float4 loads, 16B-aligned)
__device__ __forceinline__ bf16x8 ldf8_bf(const float* p) {
    const float4* q = reinterpret_cast<const float4*>(p);
    float4 u = q[0], v = q[1];
    bf16x8 r;
    r[0] = (__bf16)u.x; r[1] = (__bf16)u.y; r[2] = (__bf16)u.z; r[3] = (__bf16)u.w;
    r[4] = (__bf16)v.x; r[5] = (__bf16)v.y; r[6] = (__bf16)v.z; r[7] = (__bf16)v.w;
    return r;
}

__device__ __forceinline__ float sigmoid_f(float x) {
    return 1.0f / (1.0f + __expf(-x));
}
__device__ __forceinline__ float tanh_f(float x) {
    float e = __expf(2.0f * x);
    return 1.0f - 2.0f / (e + 1.0f);
}

// -------- K1: xh[r][n] = emb[X[r]] @ W_e2i^T + b_e2i   (r = b*T + t, 32768 rows)
__global__ __launch_bounds__(256) void k1_xh(const int* __restrict__ X,
                                             const float* __restrict__ emb,
                                             const float* __restrict__ We,
                                             const float* __restrict__ be,
                                             bf16_t* __restrict__ xh) {
    int r0 = blockIdx.x * 16;
    int lane = threadIdx.x & 63;
    int w2 = threadIdx.x >> 6;       // wave 0..3
    int quad = lane >> 4, col = lane & 15;

    int v = X[r0 + col];             // A row m = lane&15
    bf16x8 a[4];
#pragma unroll
    for (int kc = 0; kc < 4; ++kc)
        a[kc] = ldf8_bf(emb + (size_t)v * EE + kc * 32 + quad * 8);

#pragma unroll
    for (int tl = 0; tl < 2; ++tl) {
        int n = 32 * w2 + 16 * tl + col;     // B row n = lane&15
        floatx4 acc = {0.f, 0.f, 0.f, 0.f};
#pragma unroll
        for (int kc = 0; kc < 4; ++kc) {
            bf16x8 bw = ldf8_bf(We + (size_t)n * EE + kc * 32 + quad * 8);
            acc = __builtin_amdgcn_mfma_f32_16x16x32_bf16(a[kc], bw, acc, 0, 0, 0);
        }
        float bias = be[n];
#pragma unroll
        for (int r = 0; r < 4; ++r) {
            int row = quad * 4 + r;          // C/D row
            xh[(size_t)(r0 + row) * HH + n] = (bf16_t)(acc[r] + bias);
        }
    }
}

// -------- K2: gx[dir][t][b][384] = xh @ Wih^T + bih  (bf16 scratch)
__global__ __launch_bounds__(256) void k2_gx(const bf16_t* __restrict__ xh,
                                             const float* __restrict__ Wf,
                                             const float* __restrict__ bf_,
                                             const float* __restrict__ Wb,
                                             const float* __restrict__ bb_,
                                             bf16_t* __restrict__ gx) {
    int dir = blockIdx.y;
    const float* W = dir ? Wb : Wf;
    const float* bi = dir ? bb_ : bf_;
    int r0 = blockIdx.x * 16;
    int lane = threadIdx.x & 63;
    int w2 = threadIdx.x >> 6;
    int quad = lane >> 4, col = lane & 15;

    bf16x8 a[4];
#pragma unroll
    for (int kc = 0; kc < 4; ++kc)
        a[kc] = ldb8(xh + (size_t)(r0 + col) * HH + kc * 32 + quad * 8);

    int b = r0 >> 9;         // r = b*T + t
    int tbase = r0 & 511;

#pragma unroll
    for (int tl = 0; tl < 6; ++tl) {
        int tile = w2 * 6 + tl;          // 0..23
        int n = 16 * tile + col;         // 0..383
        floatx4 acc = {0.f, 0.f, 0.f, 0.f};
#pragma unroll
        for (int kc = 0; kc < 4; ++kc) {
            bf16x8 bw = ldf8_bf(W + (size_t)n * HH + kc * 32 + quad * 8);
            acc = __builtin_amdgcn_mfma_f32_16x16x32_bf16(a[kc], bw, acc, 0, 0, 0);
        }
        float bias = bi[n];
#pragma unroll
        for (int r = 0; r < 4; ++r) {
            int row = quad * 4 + r;
            int t = tbase + row;
            gx[(((size_t)dir * TT + t) * BB + b) * 384 + n] = (bf16_t)(acc[r] + bias);
        }
    }
}

// -------- K3: masked GRU recurrence, both directions.
// grid (4 groups of 16 samples, 2 dirs), 512 threads = 8 waves.
// Wave w owns gate columns j = 16w..16w+15 for all three gates (tiles w, w+8, w+16):
// r/z/n for the same (sample, j) land in the same lane+reg -> in-register gate math.
__global__ __launch_bounds__(512) void k3_gru(const bf16_t* __restrict__ gx,
                                              const float* __restrict__ Whh_f,
                                              const float* __restrict__ bhh_f,
                                              const float* __restrict__ Whh_b,
                                              const float* __restrict__ bhh_b,
                                              const int* __restrict__ lens,
                                              bf16_t* __restrict__ hist) {
    int g = blockIdx.x;      // sample group: samples 16g..16g+15
    int dir = blockIdx.y;
    const float* Whh = dir ? Whh_b : Whh_f;
    const float* bhh = dir ? bhh_b : bhh_f;

    int tid = threadIdx.x;
    int w = tid >> 6;        // wave 0..7
    int lane = tid & 63;
    int quad = lane >> 4, col = lane & 15;
    int j = 16 * w + col;    // owned hidden column

    __shared__ bf16_t hl[16 * 136];   // h (bf16) padded rows: stride 136 breaks bank conflicts
    for (int i = tid; i < 16 * 136; i += 512) hl[i] = (bf16_t)0.f;

    int bloc[4], len4[4];
    float h[4] = {0.f, 0.f, 0.f, 0.f};
#pragma unroll
    for (int r = 0; r < 4; ++r) {
        bloc[r] = quad * 4 + r;
        len4[r] = lens[16 * g + bloc[r]];
    }
    float bhr = bhh[j];
    float bhz = bhh[128 + j];
    float bhn = bhh[256 + j];

    // Whh B-fragments (bf16-rounded), resident for all 512 steps (48 VGPRs)
    bf16x8 Bw[3][4];
#pragma unroll
    for (int gate = 0; gate < 3; ++gate)
#pragma unroll
        for (int kc = 0; kc < 4; ++kc)
            Bw[gate][kc] = ldf8_bf(Whh + (size_t)(gate * 128 + j) * HH + kc * 32 + quad * 8);

    size_t dbase = (size_t)dir * TT;

    // preload gx for first step
    float gxc[3][4];
    {
        int t0 = dir ? (TT - 1) : 0;
#pragma unroll
        for (int gate = 0; gate < 3; ++gate)
#pragma unroll
            for (int r = 0; r < 4; ++r)
                gxc[gate][r] = (float)gx[((dbase + t0) * BB + 16 * g + bloc[r]) * 384 + gate * 128 + j];
    }
    __syncthreads();

    for (int s = 0; s < TT; ++s) {
        int t = dir ? (TT - 1 - s) : s;

        // A fragments from LDS h  (A row m = lane&15 = col)
        bf16x8 a[4];
#pragma unroll
        for (int kc = 0; kc < 4; ++kc)
            a[kc] = ldb8(hl + col * 136 + kc * 32 + quad * 8);

        floatx4 accr = {0.f, 0.f, 0.f, 0.f};
        floatx4 accz = {0.f, 0.f, 0.f, 0.f};
        floatx4 accn = {0.f, 0.f, 0.f, 0.f};
#pragma unroll
        for (int kc = 0; kc < 4; ++kc) {
            accr = __builtin_amdgcn_mfma_f32_16x16x32_bf16(a[kc], Bw[0][kc], accr, 0, 0, 0);
            accz = __builtin_amdgcn_mfma_f32_16x16x32_bf16(a[kc], Bw[1][kc], accz, 0, 0, 0);
            accn = __builtin_amdgcn_mfma_f32_16x16x32_bf16(a[kc], Bw[2][kc], accn, 0, 0, 0);
        }

        // prefetch next step's gx (hides L2/LLC latency behind gates+barriers)
        float gxn_[3][4] = {{0.f,0.f,0.f,0.f},{0.f,0.f,0.f,0.f},{0.f,0.f,0.f,0.f}};
        if (s < TT - 1) {
            int tn = dir ? (TT - 2 - s) : (s + 1);
#pragma unroll
            for (int gate = 0; gate < 3; ++gate)
#pragma unroll
                for (int r = 0; r < 4; ++r)
                    gxn_[gate][r] = (float)gx[((dbase + tn) * BB + 16 * g + bloc[r]) * 384 + gate * 128 + j];
        }

        // gates + state update (D row = quad*4+reg = local sample, D col = j)
#pragma unroll
        for (int r = 0; r < 4; ++r) {
            float rg = sigmoid_f(gxc[0][r] + accr[r] + bhr);
            float zg = sigmoid_f(gxc[1][r] + accz[r] + bhz);
            float ng = tanh_f(gxc[2][r] + rg * (accn[r] + bhn));
            float hn = ng + zg * (h[r] - ng);
            h[r] = (t < len4[r]) ? hn : h[r];
            hist[((dbase + t) * BB + 16 * g + bloc[r]) * HH + j] = (bf16_t)h[r];
        }

        __syncthreads();   // all A-frag reads of this step done
#pragma unroll
        for (int r = 0; r < 4; ++r)
            hl[bloc[r] * 136 + j] = (bf16_t)h[r];
        __syncthreads();   // new h visible

#pragma unroll
        for (int gate = 0; gate < 3; ++gate)
#pragma unroll
            for (int r = 0; r < 4; ++r)
                gxc[gate][r] = gxn_[gate][r];
    }
}

// -------- K4: Y = tanh(Hout @ W_h2o^T + b), score = sum(Y*u_w) ; scores[b][t] fp32
__global__ __launch_bounds__(256) void k4_scores(const bf16_t* __restrict__ hist,
                                                 const float* __restrict__ Wh2o,
                                                 const float* __restrict__ bh2o,
                                                 const float* __restrict__ uw,
                                                 float* __restrict__ scores) {
    int tile = blockIdx.x;          // rows r = t*64 + b
    int r0 = tile * 16;
    int t = r0 >> 6;
    int b0 = r0 & 63;
    int lane = threadIdx.x & 63;
    int w2 = threadIdx.x >> 6;
    int quad = lane >> 4, col = lane & 15;

    // A fragments: Hout row (b0+col), K=256 split: kc 0..3 from h_f, 4..7 from h_b
    bf16x8 a[8];
    int brow = b0 + col;
#pragma unroll
    for (int kc = 0; kc < 8; ++kc) {
        int dir = kc >> 2;
        int k0 = (kc & 3) * 32;
        a[kc] = ldb8(hist + (((size_t)dir * TT + t) * BB + brow) * HH + k0 + quad * 8);
    }

    float p4[4] = {0.f, 0.f, 0.f, 0.f};
#pragma unroll
    for (int tl = 0; tl < 2; ++tl) {
        int n = 32 * w2 + 16 * tl + col;
        floatx4 acc = {0.f, 0.f, 0.f, 0.f};
#pragma unroll
        for (int kc = 0; kc < 8; ++kc) {
            bf16x8 bw = ldf8_bf(Wh2o + (size_t)n * 256 + kc * 32 + quad * 8);
            acc = __builtin_amdgcn_mfma_f32_16x16x32_bf16(a[kc], bw, acc, 0, 0, 0);
        }
        float bias = bh2o[n];
        float u = uw[n];
#pragma unroll
        for (int r = 0; r < 4; ++r) {
            float y = tanh_f(acc[r] + bias);
            p4[r] += y * u;
        }
    }
    // reduce over the 16 cols of this quad group (rows = quad*4+r identical across them)
#pragma unroll
    for (int m = 1; m < 16; m <<= 1)
#pragma unroll
        for (int r = 0; r < 4; ++r)
            p4[r] += __shfl_xor(p4[r], m, 64);

    __shared__ float part[16][4];
    if (col == 0) {
#pragma unroll
        for (int r = 0; r < 4; ++r) part[quad * 4 + r][w2] = p4[r];
    }
    __syncthreads();
    if (threadIdx.x < 16) {
        float s = part[threadIdx.x][0] + part[threadIdx.x][1] +
                  part[threadIdx.x][2] + part[threadIdx.x][3];
        scores[(size_t)(b0 + threadIdx.x) * TT + t] = s;
    }
}

// -------- K5: per-sample softmax over valid t + pooled = sum_t alpha[t]*Hout[b][t][:]
__global__ __launch_bounds__(256) void k5_pool(const float* __restrict__ scores,
                                               const bf16_t* __restrict__ hist,
                                               const int* __restrict__ lens,
                                               float* __restrict__ out) {
    int b = blockIdx.x;
    int tid = threadIdx.x;
    int len = lens[b];
    __shared__ float alpha[TT];
    __shared__ float red[256];
    const float* srow = scores + (size_t)b * TT;

    float m = -1e30f;
    for (int t = tid; t < len; t += 256) m = fmaxf(m, srow[t]);
    red[tid] = m;
    __syncthreads();
    for (int s = 128; s > 0; s >>= 1) {
        if (tid < s) red[tid] = fmaxf(red[tid], red[tid + s]);
        __syncthreads();
    }
    float mx = red[0];
    __syncthreads();

    float sum = 0.f;
    for (int t = tid; t < TT; t += 256) {
        float e = (t < len) ? __expf(srow[t] - mx) : 0.f;
        alpha[t] = e;
        sum += e;
    }
    red[tid] = sum;
    __syncthreads();
    for (int s = 128; s > 0; s >>= 1) {
        if (tid < s) red[tid] += red[tid + s];
        __syncthreads();
    }
    float inv = 1.0f / red[0];
    __syncthreads();

    int c = tid;                 // 0..255 output channel
    int dir = c >> 7;
    int j = c & 127;
    const bf16_t* hbase = hist + ((size_t)dir * TT * BB + b) * HH + j;
    float acc = 0.f;
    int t = 0;
    for (; t + 4 <= len; t += 4) {
        acc += alpha[t + 0] * (float)hbase[(size_t)(t + 0) * BB * HH];
        acc += alpha[t + 1] * (float)hbase[(size_t)(t + 1) * BB * HH];
        acc += alpha[t + 2] * (float)hbase[(size_t)(t + 2) * BB * HH];
        acc += alpha[t + 3] * (float)hbase[(size_t)(t + 3) * BB * HH];
    }
    for (; t < len; ++t) acc += alpha[t] * (float)hbase[(size_t)t * BB * HH];

    out[(size_t)b * 256 + c] = acc * inv;
}

extern "C" void kernel_launch(void* const* d_in, const int* in_sizes, int n_in,
                              void* d_out, int out_size, void* d_ws, size_t ws_size,
                              hipStream_t stream) {
    const int* X       = (const int*)d_in[0];
    const int* lens    = (const int*)d_in[1];
    const float* emb   = (const float*)d_in[3];
    const float* We2i  = (const float*)d_in[4];
    const float* be2i  = (const float*)d_in[5];
    const float* Wihf  = (const float*)d_in[6];
    const float* Whhf  = (const float*)d_in[7];
    const float* bihf  = (const float*)d_in[8];
    const float* bhhf  = (const float*)d_in[9];
    const float* Wihb  = (const float*)d_in[10];
    const float* Whhb  = (const float*)d_in[11];
    const float* bihb  = (const float*)d_in[12];
    const float* bhhb  = (const float*)d_in[13];
    const float* Wh2o  = (const float*)d_in[14];
    const float* bh2o  = (const float*)d_in[15];
    const float* uw    = (const float*)d_in[16];

    char* ws = (char*)d_ws;
    size_t off = 0;
    bf16_t* xh = (bf16_t*)(ws + off);   off += (size_t)BB * TT * HH * 2;            // 8.4 MB
    bf16_t* gx = (bf16_t*)(ws + off);   off += (size_t)2 * TT * BB * 384 * 2;       // 50.3 MB
    bf16_t* hist = (bf16_t*)(ws + off); off += (size_t)2 * TT * BB * HH * 2;        // 16.8 MB
    float* scores = (float*)(ws + off); off += (size_t)BB * TT * 4;                 // 0.13 MB

    float* out = (float*)d_out;

    k1_xh<<<dim3(BB * TT / 16), dim3(256), 0, stream>>>(X, emb, We2i, be2i, xh);
    k2_gx<<<dim3(BB * TT / 16, 2), dim3(256), 0, stream>>>(xh, Wihf, bihf, Wihb, bihb, gx);
    k3_gru<<<dim3(4, 2), dim3(512), 0, stream>>>(gx, Whhf, bhhf, Whhb, bhhb, lens, hist);
    k4_scores<<<dim3(BB * TT / 16), dim3(256), 0, stream>>>(hist, Wh2o, bh2o, uw, scores);
    k5_pool<<<dim3(BB), dim3(256), 0, stream>>>(scores, hist, lens, out);
}